// Round 3
// baseline (10525.637 us; speedup 1.0000x reference)
//
#include <hip/hip_runtime.h>
#include <hip/hip_bf16.h>
#include <math.h>

#define B_ 128
#define T_ 2048
#define D_ 256
#define U_ 512
#define G4_ 2048
#define KT_ 768            // 512 (recurrent) + 256 (input) k-rows, transposed layout
#define ALPHA_ 0.001f

#define NGROUP 8           // batch groups
#define GB 16              // samples per group
#define NSLICE 16          // u-slices per group
#define SU 32              // u per slice
#define NWG (NGROUP*NSLICE) // 128
#define NTH 256
#define BU (B_*U_)

typedef __attribute__((ext_vector_type(8))) short bf16x8;
typedef __attribute__((ext_vector_type(4))) float f32x4;
typedef __attribute__((ext_vector_type(4))) int i32x4;
typedef __attribute__((ext_vector_type(4))) unsigned short us4;

// workspace layout (bytes)
#define OFF_WT 0                       // transposed bf16 weights: G4_*KT_*2 = 3 MiB
#define OFF_H32 (G4_*KT_*2)            // 2 tagged h buffers: 2*BU*4 = 512 KiB

__device__ __forceinline__ unsigned short f2b(float f) {
  unsigned u = __builtin_bit_cast(unsigned, f);
  u += 0x7fffu + ((u >> 16) & 1u);   // round-to-nearest-even bf16
  return (unsigned short)(u >> 16);
}

__device__ __forceinline__ float ftanh(float v) {
  v = fminf(fmaxf(v, -15.f), 15.f);
  float e = __expf(2.f * v);
  return (e - 1.f) * __builtin_amdgcn_rcpf(e + 1.f);
}

// weights transposed to [col][k] so fragment loads are contiguous 16B
__global__ void prep_kernel(const float* __restrict__ kern,
                            const float* __restrict__ rker,
                            const float* __restrict__ h0,
                            unsigned short* __restrict__ wt,
                            unsigned* __restrict__ h32) {
  int idx = blockIdx.x * blockDim.x + threadIdx.x;
  int stride = gridDim.x * blockDim.x;
  for (int i = idx; i < G4_ * KT_; i += stride) {
    int col = i / KT_, k = i - col * KT_;
    float v = (k < U_) ? rker[(size_t)k * G4_ + col]
                       : kern[(size_t)(k - U_) * G4_ + col];
    wt[i] = f2b(v);
  }
  for (int i = idx; i < BU; i += stride) {
    h32[i] = ((unsigned)f2b(h0[i]) << 16);   // tag 0 = state entering step 0
    h32[BU + i] = 0xFFFFu;                   // impossible tag (clears stale runs)
  }
}

#define LOAD8()                                                        \
  asm volatile(                                                        \
      "global_load_dwordx4 %0, %8, off sc0 sc1\n\t"                    \
      "global_load_dwordx4 %1, %8, off offset:16 sc0 sc1\n\t"          \
      "global_load_dwordx4 %2, %8, off offset:32 sc0 sc1\n\t"          \
      "global_load_dwordx4 %3, %8, off offset:48 sc0 sc1\n\t"          \
      "global_load_dwordx4 %4, %8, off offset:64 sc0 sc1\n\t"          \
      "global_load_dwordx4 %5, %8, off offset:80 sc0 sc1\n\t"          \
      "global_load_dwordx4 %6, %8, off offset:96 sc0 sc1\n\t"          \
      "global_load_dwordx4 %7, %8, off offset:112 sc0 sc1"             \
      : "=&v"(v0), "=&v"(v1), "=&v"(v2), "=&v"(v3),                    \
        "=&v"(v4), "=&v"(v5), "=&v"(v6), "=&v"(v7)                     \
      : "v"(pbase));                                                   \
  __builtin_amdgcn_sched_barrier(0)

#define FENCE8()                                                       \
  asm volatile("s_waitcnt vmcnt(0)"                                    \
      : "+v"(v0), "+v"(v1), "+v"(v2), "+v"(v3),                        \
        "+v"(v4), "+v"(v5), "+v"(v6), "+v"(v7));                       \
  __builtin_amdgcn_sched_barrier(0)

#define CKV(vv) ((((unsigned)(vv)[0] ^ tgv) & 0xffffu) |               \
                 (((unsigned)(vv)[1] ^ tgv) & 0xffffu) |               \
                 (((unsigned)(vv)[2] ^ tgv) & 0xffffu) |               \
                 (((unsigned)(vv)[3] ^ tgv) & 0xffffu))

#define PK(lo, hi) (int)(((unsigned)(hi) & 0xffff0000u) | ((unsigned)(lo) >> 16))

__global__ __launch_bounds__(NTH, 1) void plstm_kernel(
    const float* __restrict__ x, const float* __restrict__ h0,
    const float* __restrict__ c0, const float* __restrict__ t0,
    const float* __restrict__ bias, const float* __restrict__ tg,
    const unsigned short* __restrict__ wt,
    unsigned* h32, float* __restrict__ out) {
  const int wg = blockIdx.x;
  const int g = wg >> 4, sl = wg & 15;
  const int b0 = g * GB, u0 = sl * SU;
  const int tid = threadIdx.x;
  const int wave = tid >> 6, lane = tid & 63;

  __shared__ unsigned short h_lds[2][GB * U_];   // 2 x 16 KiB
  __shared__ unsigned short x_lds[2][GB * D_];   // 2 x 8 KiB
  __shared__ float z_lds[2][GB][130];            // 2 x 8.3 KiB (pad->conflict-free)

  // ---- weight fragments (transposed layout: contiguous 16B per frag) ----
  bf16x8 br0[16], br1[16], bx0[8], bx1[8];
  {
    const int kr0 = (lane >> 4) * 8;
    const int col0 = wave * U_ + u0 + (lane & 15);
    const unsigned short* w0 = wt + (size_t)col0 * KT_;
    const unsigned short* w1 = wt + (size_t)(col0 + 16) * KT_;
#pragma unroll
    for (int kt = 0; kt < 16; ++kt) {
      br0[kt] = *(const bf16x8*)(w0 + kt * 32 + kr0);
      br1[kt] = *(const bf16x8*)(w1 + kt * 32 + kr0);
    }
#pragma unroll
    for (int kt = 0; kt < 8; ++kt) {
      bx0[kt] = *(const bf16x8*)(w0 + U_ + kt * 32 + kr0);
      bx1[kt] = *(const bf16x8*)(w1 + U_ + kt * 32 + kr0);
    }
  }
  const float bias0 = bias[wave * U_ + u0 + (lane & 15)];
  const float bias1 = bias[wave * U_ + u0 + 16 + (lane & 15)];

  // ---- per-thread elementwise state: (sample s=row, u = u0+j and u0+16+j) ----
  const int row = tid >> 4;      // sample within group
  const int chunk = tid & 15;    // 32-u chunk this thread polls/stages
  const int bb = b0 + row;
  const int ua = u0 + chunk, ub = u0 + 16 + chunk;
  float c_a = c0[bb * U_ + ua], c_b = c0[bb * U_ + ub];
  float h_a = h0[bb * U_ + ua], h_b = h0[bb * U_ + ub];
  const float t0a = t0[bb * U_ + ua], t0b = t0[bb * U_ + ub];
  const float per_a = tg[ua], per_b = tg[ub];
  const float sh_a = tg[U_ + ua], sh_b = tg[U_ + ub];
  const float ro_a = tg[2 * U_ + ua], ro_b = tg[2 * U_ + ub];

  const int arow = lane & 15;
  const int koff = (lane >> 4) * 16;
  const int swzA = (arow & 7) << 4;
  const int swzR = (row & 7) << 4;

  auto stage_x = [&](int t, int buf) {
    const int f0 = chunk * 16;
    const float* xp = x + ((size_t)bb * T_ + t) * D_ + f0;
    char* base = (char*)&x_lds[buf][0];
#pragma unroll
    for (int q = 0; q < 4; ++q) {
      float4 v = *(const float4*)(xp + q * 4);
      us4 pk = { f2b(v.x), f2b(v.y), f2b(v.z), f2b(v.w) };
      *(us4*)(base + ((row * 512 + (f0 + q * 4) * 2) ^ swzR)) = pk;
    }
  };

  stage_x(0, 0);
  stage_x(1, 1);
  __syncthreads();

  for (int step = 0; step < T_; ++step) {
    const int par = step & 1;

    // ---- (1) issue tagged-h poll loads (32 entries = one producer slice) ----
    const unsigned* pbase = h32 + (size_t)par * BU + bb * U_ + chunk * 32;
    i32x4 v0, v1, v2, v3, v4, v5, v6, v7;
    LOAD8();

    // ---- (2) x-partial GEMM overlaps the poll-load latency ----
    f32x4 acc0 = { bias0, bias0, bias0, bias0 };
    f32x4 acc1 = { bias1, bias1, bias1, bias1 };
    {
      const char* xb = (const char*)&x_lds[par][0];
#pragma unroll
      for (int kt = 0; kt < 8; ++kt) {
        bf16x8 a = *(const bf16x8*)(xb + ((arow * 512 + kt * 64 + koff) ^ swzA));
        acc0 = __builtin_amdgcn_mfma_f32_16x16x32_bf16(a, bx0[kt], acc0, 0, 0, 0);
        acc1 = __builtin_amdgcn_mfma_f32_16x16x32_bf16(a, bx1[kt], acc1, 0, 0, 0);
      }
    }

    // ---- (3) poll: all 32 tags must equal step ----
    const unsigned tgv = (unsigned)step;
    for (;;) {
      FENCE8();
      unsigned bad = CKV(v0) | CKV(v1) | CKV(v2) | CKV(v3) |
                     CKV(v4) | CKV(v5) | CKV(v6) | CKV(v7);
      if (!bad) break;
      __builtin_amdgcn_s_sleep(1);
      LOAD8();
    }

    // ---- (4) strip tags, pack bf16 pairs -> swizzled h_lds[par] ----
    {
      char* hdst = (char*)&h_lds[par][0];
      const int base_b = row * 1024 + chunk * 64;
      i32x4 w;
      w = i32x4{ PK(v0[0], v0[1]), PK(v0[2], v0[3]), PK(v1[0], v1[1]), PK(v1[2], v1[3]) };
      *(i32x4*)(hdst + ((base_b + 0) ^ swzR)) = w;
      w = i32x4{ PK(v2[0], v2[1]), PK(v2[2], v2[3]), PK(v3[0], v3[1]), PK(v3[2], v3[3]) };
      *(i32x4*)(hdst + ((base_b + 16) ^ swzR)) = w;
      w = i32x4{ PK(v4[0], v4[1]), PK(v4[2], v4[3]), PK(v5[0], v5[1]), PK(v5[2], v5[3]) };
      *(i32x4*)(hdst + ((base_b + 32) ^ swzR)) = w;
      w = i32x4{ PK(v6[0], v6[1]), PK(v6[2], v6[3]), PK(v7[0], v7[1]), PK(v7[2], v7[3]) };
      *(i32x4*)(hdst + ((base_b + 48) ^ swzR)) = w;
    }
    __syncthreads();   // S1: h_lds[par] ready

    // ---- (5) recurrent GEMM ----
    {
      const char* hbm = (const char*)&h_lds[par][0];
#pragma unroll
      for (int kt = 0; kt < 16; ++kt) {
        bf16x8 a = *(const bf16x8*)(hbm + ((arow * 1024 + kt * 64 + koff) ^ swzA));
        acc0 = __builtin_amdgcn_mfma_f32_16x16x32_bf16(a, br0[kt], acc0, 0, 0, 0);
        acc1 = __builtin_amdgcn_mfma_f32_16x16x32_bf16(a, br1[kt], acc1, 0, 0, 0);
      }
    }
    if (step + 2 < T_) stage_x(step + 2, par);   // safe: readers past S1, next read after S2

    // ---- (6) z exchange (C/D: col=lane&15, row=(lane>>4)*4+r) ----
#pragma unroll
    for (int r2 = 0; r2 < 4; ++r2) {
      z_lds[par][(lane >> 4) * 4 + r2][wave * 32 + (lane & 15)] = acc0[r2];
      z_lds[par][(lane >> 4) * 4 + r2][wave * 32 + 16 + (lane & 15)] = acc1[r2];
    }
    __syncthreads();   // S2: z ready

    // ---- (7) gates + phased time gate + tagged h broadcast ----
    {
      const float* zr = &z_lds[par][row][0];
      const float zi_a = zr[chunk],      zf_a = zr[32 + chunk];
      const float zc_a = zr[64 + chunk], zo_a = zr[96 + chunk];
      const float zi_b = zr[16 + chunk], zf_b = zr[48 + chunk];
      const float zc_b = zr[80 + chunk], zo_b = zr[112 + chunk];

      const float tt = t0a + (float)(step + 1);   // t0 identical across u here

      float ig = fminf(fmaxf(0.2f * zi_a + 0.5f, 0.f), 1.f);
      float fg = fminf(fmaxf(0.2f * zf_a + 0.5f, 0.f), 1.f);
      float og = fminf(fmaxf(0.2f * zo_a + 0.5f, 0.f), 1.f);
      float chat = fg * c_a + ig * ftanh(zc_a);
      float hhat = og * ftanh(chat);
      float xx = tt - sh_a;
      float ph = (xx - per_a * floorf(xx / per_a)) / per_a;
      float kk = (ph <= 0.5f * ro_a) ? (2.f * ph / ro_a)
               : ((ph <= ro_a) ? (2.f - 2.f * ph / ro_a) : (ALPHA_ * ph));
      c_a = kk * chat + (1.f - kk) * c_a;
      h_a = kk * hhat + (1.f - kk) * h_a;

      float tb = t0b + (float)(step + 1);
      ig = fminf(fmaxf(0.2f * zi_b + 0.5f, 0.f), 1.f);
      fg = fminf(fmaxf(0.2f * zf_b + 0.5f, 0.f), 1.f);
      og = fminf(fmaxf(0.2f * zo_b + 0.5f, 0.f), 1.f);
      chat = fg * c_b + ig * ftanh(zc_b);
      hhat = og * ftanh(chat);
      xx = tb - sh_b;
      ph = (xx - per_b * floorf(xx / per_b)) / per_b;
      kk = (ph <= 0.5f * ro_b) ? (2.f * ph / ro_b)
         : ((ph <= ro_b) ? (2.f - 2.f * ph / ro_b) : (ALPHA_ * ph));
      c_b = kk * chat + (1.f - kk) * c_b;
      h_b = kk * hhat + (1.f - kk) * h_b;

      float* op = out + ((size_t)bb * T_ + step) * U_;
      op[ua] = h_a;
      op[ub] = h_b;

      unsigned* hn = h32 + (size_t)((step + 1) & 1) * BU + bb * U_;
      const unsigned tagn = (unsigned)(step + 1);
      unsigned va = ((unsigned)f2b(h_a) << 16) | tagn;
      unsigned vb = ((unsigned)f2b(h_b) << 16) | tagn;
      const unsigned* pa_ = hn + ua;
      const unsigned* pb_ = hn + ub;
      asm volatile("global_store_dword %0, %1, off sc0 sc1"
                   :: "v"(pa_), "v"(va) : "memory");
      asm volatile("global_store_dword %0, %1, off sc0 sc1"
                   :: "v"(pb_), "v"(vb) : "memory");
    }
    // no end-of-step barrier: tag dataflow + S1/S2 cover all LDS hazards
  }
}

extern "C" void kernel_launch(void* const* d_in, const int* in_sizes, int n_in,
                              void* d_out, int out_size, void* d_ws,
                              size_t ws_size, hipStream_t stream) {
  const float* x    = (const float*)d_in[0];
  const float* h0   = (const float*)d_in[1];
  const float* c0   = (const float*)d_in[2];
  const float* t0   = (const float*)d_in[3];
  const float* kern = (const float*)d_in[4];
  const float* rker = (const float*)d_in[5];
  const float* bias = (const float*)d_in[6];
  const float* tg   = (const float*)d_in[7];
  float* out = (float*)d_out;

  char* ws = (char*)d_ws;
  unsigned short* wt = (unsigned short*)(ws + OFF_WT);
  unsigned* h32      = (unsigned*)(ws + OFF_H32);

  prep_kernel<<<1024, 256, 0, stream>>>(kern, rker, h0, wt, h32);
  plstm_kernel<<<NWG, NTH, 0, stream>>>(x, h0, c0, t0, bias, tg, wt, h32, out);
}

// Round 4
// 6519.662 us; speedup vs baseline: 1.6144x; 1.6144x over previous
//
#include <hip/hip_runtime.h>
#include <hip/hip_bf16.h>
#include <math.h>

#define B_ 128
#define T_ 2048
#define D_ 256
#define U_ 512
#define G4_ 2048
#define KT_ 768            // 512 (recurrent) + 256 (input) k-rows, transposed layout
#define ALPHA_ 0.001f

#define NGROUP 8           // batch groups (one per XCD)
#define GB 16              // samples per group
#define NSLICE 16          // u-slices per group
#define SU 32              // u per slice
#define NWG (NGROUP*NSLICE) // 128
#define NTH 256
#define BU (B_*U_)

typedef __attribute__((ext_vector_type(8))) short bf16x8;
typedef __attribute__((ext_vector_type(4))) float f32x4;
typedef __attribute__((ext_vector_type(4))) int i32x4;
typedef __attribute__((ext_vector_type(2))) int i32x2;
typedef __attribute__((ext_vector_type(4))) unsigned short us4;

// workspace layout (bytes)
#define OFF_WT 0                       // transposed bf16 weights: G4_*KT_*2 = 3 MiB
#define OFF_H32 (G4_*KT_*2)            // 2 tagged h buffers: 2*BU*4 = 512 KiB

__device__ __forceinline__ unsigned short f2b(float f) {
  unsigned u = __builtin_bit_cast(unsigned, f);
  u += 0x7fffu + ((u >> 16) & 1u);   // round-to-nearest-even bf16
  return (unsigned short)(u >> 16);
}

__device__ __forceinline__ float ftanh(float v) {
  v = fminf(fmaxf(v, -15.f), 15.f);
  float e = __expf(2.f * v);
  return (e - 1.f) * __builtin_amdgcn_rcpf(e + 1.f);
}

// weights transposed to [col][k] so fragment loads are contiguous 16B
__global__ void prep_kernel(const float* __restrict__ kern,
                            const float* __restrict__ rker,
                            const float* __restrict__ h0,
                            unsigned short* __restrict__ wt,
                            unsigned* __restrict__ h32) {
  int idx = blockIdx.x * blockDim.x + threadIdx.x;
  int stride = gridDim.x * blockDim.x;
  for (int i = idx; i < G4_ * KT_; i += stride) {
    int col = i / KT_, k = i - col * KT_;
    float v = (k < U_) ? rker[(size_t)k * G4_ + col]
                       : kern[(size_t)(k - U_) * G4_ + col];
    wt[i] = f2b(v);
  }
  for (int i = idx; i < BU; i += stride) {
    h32[i] = ((unsigned)f2b(h0[i]) << 16);   // tag 0 = state entering step 0
    h32[BU + i] = 0xFFFFu;                   // impossible tag (clears stale runs)
  }
}

// coalesced poll: per instruction, 64 lanes x 16B = 1KB contiguous
#define LOAD8()                                                        \
  asm volatile(                                                        \
      "global_load_dwordx4 %0, %8, off sc0 sc1\n\t"                    \
      "global_load_dwordx4 %1, %8, off offset:1024 sc0 sc1\n\t"        \
      "global_load_dwordx4 %2, %8, off offset:2048 sc0 sc1\n\t"        \
      "global_load_dwordx4 %3, %8, off offset:3072 sc0 sc1\n\t"        \
      "global_load_dwordx4 %4, %9, off sc0 sc1\n\t"                    \
      "global_load_dwordx4 %5, %9, off offset:1024 sc0 sc1\n\t"        \
      "global_load_dwordx4 %6, %9, off offset:2048 sc0 sc1\n\t"        \
      "global_load_dwordx4 %7, %9, off offset:3072 sc0 sc1"            \
      : "=&v"(v0), "=&v"(v1), "=&v"(v2), "=&v"(v3),                    \
        "=&v"(v4), "=&v"(v5), "=&v"(v6), "=&v"(v7)                     \
      : "v"(ppoll), "v"(ppoll2));                                      \
  __builtin_amdgcn_sched_barrier(0)

#define FENCE8()                                                       \
  asm volatile("s_waitcnt vmcnt(0)"                                    \
      : "+v"(v0), "+v"(v1), "+v"(v2), "+v"(v3),                        \
        "+v"(v4), "+v"(v5), "+v"(v6), "+v"(v7));                       \
  __builtin_amdgcn_sched_barrier(0)

#define CKV(vv) ((((unsigned)(vv)[0] ^ tgv) & 0xffffu) |               \
                 (((unsigned)(vv)[1] ^ tgv) & 0xffffu) |               \
                 (((unsigned)(vv)[2] ^ tgv) & 0xffffu) |               \
                 (((unsigned)(vv)[3] ^ tgv) & 0xffffu))

#define PK(lo, hi) (int)(((unsigned)(hi) & 0xffff0000u) | ((unsigned)(lo) >> 16))

// strip tags from one 16B chunk -> 8B bf16 pair-write to swizzled LDS
#define PACK2(vv, k)                                                         \
  { const int r_ = 4 * wv + ((k) >> 1);                                      \
    const int ba_ = (r_ * 1024 + (((k) & 1) << 9) + 8 * ln) ^ ((r_ & 7) << 4); \
    i32x2 d_ = { PK((vv)[0], (vv)[1]), PK((vv)[2], (vv)[3]) };               \
    *(i32x2*)(hdst + ba_) = d_; }

__global__ __launch_bounds__(NTH, 1) void plstm_kernel(
    const float* __restrict__ x, const float* __restrict__ h0,
    const float* __restrict__ c0, const float* __restrict__ t0,
    const float* __restrict__ bias, const float* __restrict__ tg,
    const unsigned short* __restrict__ wt,
    unsigned* h32, float* __restrict__ out) {
  const int wg = blockIdx.x;
  const int g = wg & 7, sl = wg >> 3;   // group == XCD (round-robin dispatch)
  const int b0 = g * GB, u0 = sl * SU;
  const int tid = threadIdx.x;
  const int wave = tid >> 6, lane = tid & 63;

  __shared__ unsigned short h_lds[2][GB * U_];   // 2 x 16 KiB
  __shared__ unsigned short x_lds[2][GB * D_];   // 2 x 8 KiB
  __shared__ float z_lds[2][GB][130];            // pad -> conflict-free

  // ---- weight fragments (transposed layout: contiguous 16B per frag) ----
  bf16x8 br0[16], br1[16], bx0[8], bx1[8];
  {
    const int kr0 = (lane >> 4) * 8;
    const int col0 = wave * U_ + u0 + (lane & 15);
    const unsigned short* w0 = wt + (size_t)col0 * KT_;
    const unsigned short* w1 = wt + (size_t)(col0 + 16) * KT_;
#pragma unroll
    for (int kt = 0; kt < 16; ++kt) {
      br0[kt] = *(const bf16x8*)(w0 + kt * 32 + kr0);
      br1[kt] = *(const bf16x8*)(w1 + kt * 32 + kr0);
    }
#pragma unroll
    for (int kt = 0; kt < 8; ++kt) {
      bx0[kt] = *(const bf16x8*)(w0 + U_ + kt * 32 + kr0);
      bx1[kt] = *(const bf16x8*)(w1 + U_ + kt * 32 + kr0);
    }
  }
  const float bias0 = bias[wave * U_ + u0 + (lane & 15)];
  const float bias1 = bias[wave * U_ + u0 + 16 + (lane & 15)];

  // ---- per-thread elementwise state: sample=row, u = u0+2*chunk (+1) ----
  const int row = tid >> 4;
  const int chunk = tid & 15;
  const int bb = b0 + row;
  const int ua = u0 + 2 * chunk, ub = ua + 1;
  float c_a = c0[bb * U_ + ua], c_b = c0[bb * U_ + ub];
  float h_a = h0[bb * U_ + ua], h_b = h0[bb * U_ + ub];
  const float t0a = t0[bb * U_ + ua], t0b = t0[bb * U_ + ub];
  const float per_a = tg[ua], per_b = tg[ub];
  const float sh_a = tg[U_ + ua], sh_b = tg[U_ + ub];
  const float ro_a = tg[2 * U_ + ua], ro_b = tg[2 * U_ + ub];

  const int arow = lane & 15;
  const int koff = (lane >> 4) * 16;
  const int swzA = (arow & 7) << 4;
  const int swzR = (row & 7) << 4;
  const int wv = wave, ln = lane;

  auto stage_x = [&](int t, int buf) {
    const int f0 = chunk * 16;
    const float* xp = x + ((size_t)bb * T_ + t) * D_ + f0;
    char* base = (char*)&x_lds[buf][0];
#pragma unroll
    for (int q = 0; q < 4; ++q) {
      float4 v = *(const float4*)(xp + q * 4);
      us4 pk = { f2b(v.x), f2b(v.y), f2b(v.z), f2b(v.w) };
      *(us4*)(base + ((row * 512 + (f0 + q * 4) * 2) ^ swzR)) = pk;
    }
  };

  stage_x(0, 0);
  stage_x(1, 1);
  __syncthreads();

  // wave-linear poll pointers: wave w covers group-slab bytes [w*8K, (w+1)*8K)
  const unsigned* gslab0 = h32 + (size_t)b0 * U_;
  const int poff = wv * 2048 + ln * 4;   // dwords

  for (int step = 0; step < T_; ++step) {
    const int par = step & 1;

    // ---- (1) issue coalesced tagged-h poll loads ----
    const unsigned* ppoll = gslab0 + (size_t)par * BU + poff;
    const unsigned* ppoll2 = ppoll + 1024;
    i32x4 v0, v1, v2, v3, v4, v5, v6, v7;
    LOAD8();

    // ---- (2) x-partial GEMM overlaps the poll-load latency ----
    f32x4 acc0 = { bias0, bias0, bias0, bias0 };
    f32x4 acc1 = { bias1, bias1, bias1, bias1 };
    {
      const char* xb = (const char*)&x_lds[par][0];
#pragma unroll
      for (int kt = 0; kt < 8; ++kt) {
        bf16x8 a = *(const bf16x8*)(xb + ((arow * 512 + kt * 64 + koff) ^ swzA));
        acc0 = __builtin_amdgcn_mfma_f32_16x16x32_bf16(a, bx0[kt], acc0, 0, 0, 0);
        acc1 = __builtin_amdgcn_mfma_f32_16x16x32_bf16(a, bx1[kt], acc1, 0, 0, 0);
      }
    }

    // ---- (3) poll: all 32 tags must equal step ----
    const unsigned tgv = (unsigned)step;
    for (;;) {
      FENCE8();
      unsigned bad = CKV(v0) | CKV(v1) | CKV(v2) | CKV(v3) |
                     CKV(v4) | CKV(v5) | CKV(v6) | CKV(v7);
      if (!bad) break;
      __builtin_amdgcn_s_sleep(1);
      LOAD8();
    }

    // ---- (4) strip tags -> swizzled h_lds[par] (8B writes, conflict-free) ----
    {
      char* hdst = (char*)&h_lds[par][0];
      PACK2(v0, 0); PACK2(v1, 1); PACK2(v2, 2); PACK2(v3, 3);
      PACK2(v4, 4); PACK2(v5, 5); PACK2(v6, 6); PACK2(v7, 7);
    }
    __syncthreads();   // S1: h_lds[par] ready

    // ---- (5) recurrent GEMM ----
    {
      const char* hbm = (const char*)&h_lds[par][0];
#pragma unroll
      for (int kt = 0; kt < 16; ++kt) {
        bf16x8 a = *(const bf16x8*)(hbm + ((arow * 1024 + kt * 64 + koff) ^ swzA));
        acc0 = __builtin_amdgcn_mfma_f32_16x16x32_bf16(a, br0[kt], acc0, 0, 0, 0);
        acc1 = __builtin_amdgcn_mfma_f32_16x16x32_bf16(a, br1[kt], acc1, 0, 0, 0);
      }
    }

    // ---- (6) z exchange (C/D: col=lane&15, row=(lane>>4)*4+r) ----
#pragma unroll
    for (int r2 = 0; r2 < 4; ++r2) {
      z_lds[par][(lane >> 4) * 4 + r2][wave * 32 + (lane & 15)] = acc0[r2];
      z_lds[par][(lane >> 4) * 4 + r2][wave * 32 + 16 + (lane & 15)] = acc1[r2];
    }
    __syncthreads();   // S2: z ready

    // ---- (7) gates + phased time gate + tagged h broadcast ----
    {
      const float* zr = &z_lds[par][row][0];
      const int c2 = 2 * chunk;
      const float zi_a = zr[c2],      zi_b = zr[c2 + 1];
      const float zf_a = zr[32 + c2], zf_b = zr[33 + c2];
      const float zc_a = zr[64 + c2], zc_b = zr[65 + c2];
      const float zo_a = zr[96 + c2], zo_b = zr[97 + c2];

      float ig = fminf(fmaxf(0.2f * zi_a + 0.5f, 0.f), 1.f);
      float fg = fminf(fmaxf(0.2f * zf_a + 0.5f, 0.f), 1.f);
      float og = fminf(fmaxf(0.2f * zo_a + 0.5f, 0.f), 1.f);
      float chat = fg * c_a + ig * ftanh(zc_a);
      float hhat = og * ftanh(chat);
      float tt = t0a + (float)(step + 1);
      float xx = tt - sh_a;
      float ph = (xx - per_a * floorf(xx / per_a)) / per_a;
      float kk = (ph <= 0.5f * ro_a) ? (2.f * ph / ro_a)
               : ((ph <= ro_a) ? (2.f - 2.f * ph / ro_a) : (ALPHA_ * ph));
      c_a = kk * chat + (1.f - kk) * c_a;
      h_a = kk * hhat + (1.f - kk) * h_a;

      tt = t0b + (float)(step + 1);
      ig = fminf(fmaxf(0.2f * zi_b + 0.5f, 0.f), 1.f);
      fg = fminf(fmaxf(0.2f * zf_b + 0.5f, 0.f), 1.f);
      og = fminf(fmaxf(0.2f * zo_b + 0.5f, 0.f), 1.f);
      chat = fg * c_b + ig * ftanh(zc_b);
      hhat = og * ftanh(chat);
      xx = tt - sh_b;
      ph = (xx - per_b * floorf(xx / per_b)) / per_b;
      kk = (ph <= 0.5f * ro_b) ? (2.f * ph / ro_b)
         : ((ph <= ro_b) ? (2.f - 2.f * ph / ro_b) : (ALPHA_ * ph));
      c_b = kk * chat + (1.f - kk) * c_b;
      h_b = kk * hhat + (1.f - kk) * h_b;

      // tagged h broadcast (critical path) — one 8B L2-bypass store
      {
        unsigned* hn = h32 + (size_t)((step + 1) & 1) * BU + bb * U_;
        const unsigned tagn = (unsigned)(step + 1);
        i32x2 hv = { (int)(((unsigned)f2b(h_a) << 16) | tagn),
                     (int)(((unsigned)f2b(h_b) << 16) | tagn) };
        const unsigned* hp = hn + ua;
        asm volatile("global_store_dwordx2 %0, %1, off sc0 sc1"
                     :: "v"(hp), "v"(hv) : "memory");
      }
      // output write (cached, fire-and-forget)
      float2 ov; ov.x = h_a; ov.y = h_b;
      *(float2*)(out + ((size_t)bb * T_ + step) * U_ + ua) = ov;
    }

    // ---- (8) x prefetch in the slack window after the broadcast ----
    if (step + 2 < T_) stage_x(step + 2, par);
  }
}

extern "C" void kernel_launch(void* const* d_in, const int* in_sizes, int n_in,
                              void* d_out, int out_size, void* d_ws,
                              size_t ws_size, hipStream_t stream) {
  const float* x    = (const float*)d_in[0];
  const float* h0   = (const float*)d_in[1];
  const float* c0   = (const float*)d_in[2];
  const float* t0   = (const float*)d_in[3];
  const float* kern = (const float*)d_in[4];
  const float* rker = (const float*)d_in[5];
  const float* bias = (const float*)d_in[6];
  const float* tg   = (const float*)d_in[7];
  float* out = (float*)d_out;

  char* ws = (char*)d_ws;
  unsigned short* wt = (unsigned short*)(ws + OFF_WT);
  unsigned* h32      = (unsigned*)(ws + OFF_H32);

  prep_kernel<<<1024, 256, 0, stream>>>(kern, rker, h0, wt, h32);
  plstm_kernel<<<NWG, NTH, 0, stream>>>(x, h0, c0, t0, bias, tg, wt, h32, out);
}